// Round 11
// baseline (132.930 us; speedup 1.0000x reference)
//
#include <hip/hip_runtime.h>
#include <math.h>

#define Dd 32
#define Hh 256

using short8   = __attribute__((ext_vector_type(8))) short;
using floatx4  = __attribute__((ext_vector_type(4))) float;
typedef unsigned short ushort4v __attribute__((ext_vector_type(4)));

__device__ inline unsigned short f2bf(float f) {
    union { float f; unsigned u; } v; v.f = f;
    unsigned r = (v.u + 0x7FFFu + ((v.u >> 16) & 1u)) >> 16;
    return (unsigned short)r;
}
__device__ inline float bf2f(unsigned short h) {
    union { unsigned u; float f; } v; v.u = ((unsigned)h) << 16;
    return v.f;
}

// Fragment-linear layouts (16x16x32 MFMA) — see R9.
__device__ inline size_t offFrag256(int row, int k) {
    return ((size_t)((row >> 4) * 8 + (k >> 5))) * 512
         + (((k & 31) >> 3) * 16 + (row & 15)) * 8 + (k & 7);
}

// ============================================================================
// K1: weight transposes to bf16 FRAGMENT layout. grid 51 blocks. (R9 identical)
// ============================================================================
__global__ __launch_bounds__(256) void k1_prep(
    const float* __restrict__ sW1, const float* __restrict__ sW2, const float* __restrict__ sW3,
    const float* __restrict__ cW1, const float* __restrict__ cW2, const float* __restrict__ cW3,
    unsigned short* __restrict__ cW3t,
    unsigned short* __restrict__ sW2t, unsigned short* __restrict__ cW2t,
    unsigned short* __restrict__ sW3t,
    unsigned short* __restrict__ W1ts, unsigned short* __restrict__ W1tc)
{
    __shared__ float fl[64][33];
    const int tid = threadIdx.x;
    const int bid = blockIdx.x;

    if (bid < 49) {
        const float* src; unsigned short* dst; int stride, n0;
        if (bid < 32)      { src = cW3; dst = cW3t; stride = 1024; n0 = bid * 32; }
        else if (bid < 40) { src = sW2; dst = sW2t; stride = 256;  n0 = (bid - 32) * 32; }
        else if (bid < 48) { src = cW2; dst = cW2t; stride = 256;  n0 = (bid - 40) * 32; }
        else               { src = sW3; dst = sW3t; stride = 32;   n0 = 0; }

        const int nn  = tid & 31, kg = tid >> 5;
        const int nn2 = tid >> 3, ks = (tid & 7) * 8;

        for (int p = 0; p < 4; ++p) {
            if (p) __syncthreads();
            #pragma unroll
            for (int j = 0; j < 8; ++j) {
                int kk = kg * 8 + j;
                fl[kk][nn] = src[(size_t)(p * 64 + kk) * stride + n0 + nn];
            }
            __syncthreads();
            short8 v;
            #pragma unroll
            for (int j = 0; j < 8; ++j) v[j] = (short)f2bf(fl[ks + j][nn2]);
            *(short8*)(dst + offFrag256(n0 + nn2, p * 64 + ks)) = v;
        }
        return;
    }
    {
        const float* W1 = (bid == 49) ? sW1 : cW1;
        unsigned short* dst = (bid == 49) ? W1ts : W1tc;
        const int n = tid;
        #pragma unroll
        for (int c8 = 0; c8 < 4; ++c8) {
            short8 v;
            #pragma unroll
            for (int j = 0; j < 8; ++j)
                v[j] = (short)f2bf(W1[(size_t)(c8 * 8 + j) * 256 + n]);
            *(short8*)(dst + (size_t)(n >> 4) * 512 + (c8 * 16 + (n & 15)) * 8) = v;
        }
    }
}

// ============================================================================
// KA: forward MFMA (256 blocks) + Mt precompute (132 blocks). (R9 identical)
// ============================================================================
__global__ __launch_bounds__(256) void ka_mfma(
    const float* __restrict__ x,
    const float* __restrict__ sW1, const float* __restrict__ sW2, const float* __restrict__ sW3,
    const float* __restrict__ cW1, const float* __restrict__ cW2, const float* __restrict__ cW3,
    const unsigned short* __restrict__ W1ts, const unsigned short* __restrict__ W1tc,
    const unsigned short* __restrict__ sW2t, const unsigned short* __restrict__ cW2t,
    const unsigned short* __restrict__ sW3t,
    const float* __restrict__ sb1, const float* __restrict__ sb2, const float* __restrict__ sb3,
    const float* __restrict__ cb1, const float* __restrict__ cb2,
    float* __restrict__ out_score,
    unsigned short* __restrict__ T1s, unsigned short* __restrict__ T2s,
    unsigned short* __restrict__ T1c, unsigned short* __restrict__ T2c,
    unsigned short* __restrict__ H2c, unsigned short* __restrict__ Mt)
{
    __shared__ char smem[9216];
    const int tid = threadIdx.x;
    const int bid = blockIdx.x;

    if (bid >= 256) {
        const int pb = bid - 256;
        const int kq = pb & 3;
        const int i  = pb >> 2;
        float (*W1t)[36] = (float(*)[36])smem;

        const float *W1, *W2, *C3;
        int cstride, coff;
        if (i == 0) { W1 = sW1; W2 = sW2; C3 = sW3; cstride = 32;   coff = 0; }
        else        { W1 = cW1; W2 = cW2; C3 = cW3; cstride = 1024; coff = (i - 1) * 32; }

        {
            int kl = tid & 63, jg = tid >> 6;
            #pragma unroll
            for (int jj = 0; jj < 8; ++jj) {
                int j = jg * 8 + jj;
                W1t[kl][j] = W1[j * 256 + kq * 64 + kl];
            }
        }
        float ct[32];
        {
            const float* src = C3 + (size_t)tid * cstride + coff;
            #pragma unroll
            for (int j4 = 0; j4 < 8; ++j4) {
                float4 v = *(const float4*)(src + j4 * 4);
                ct[j4 * 4 + 0] = v.x; ct[j4 * 4 + 1] = v.y;
                ct[j4 * 4 + 2] = v.z; ct[j4 * 4 + 3] = v.w;
            }
        }
        __syncthreads();

        for (int kg = 0; kg < 8; ++kg) {
            const int kbase = kq * 64 + kg * 8;
            short8 pk;
            #pragma unroll
            for (int q = 0; q < 8; ++q) {
                float a = 0.f;
                #pragma unroll
                for (int j4 = 0; j4 < 8; ++j4) {
                    float4 w = *(const float4*)&W1t[kg * 8 + q][j4 * 4];
                    a += w.x * ct[j4 * 4 + 0] + w.y * ct[j4 * 4 + 1]
                       + w.z * ct[j4 * 4 + 2] + w.w * ct[j4 * 4 + 3];
                }
                float m = a * W2[(size_t)(kbase + q) * 256 + tid];
                pk[q] = (short)f2bf(m);
            }
            *(short8*)(Mt + (size_t)i * 65536 + offFrag256(tid, kbase)) = pk;
        }
        return;
    }

    const int net = bid & 1;
    const int sb  = (bid >> 1) * 16;

    const unsigned short* W1t = net ? W1tc : W1ts;
    const unsigned short* W2t = net ? cW2t : sW2t;
    const float* b1 = net ? cb1 : sb1;
    const float* b2 = net ? cb2 : sb2;
    unsigned short* T1 = net ? T1c : T1s;
    unsigned short* T2 = net ? T2c : T2s;

    unsigned short (*hB)[264] = (unsigned short(*)[264])smem;

    const int w    = tid >> 6;
    const int lane = tid & 63;
    const int g    = lane >> 4;
    const int r16  = lane & 15;

    short8 ax;
    {
        const float* xs = x + (size_t)(sb + r16) * 32 + g * 8;
        float4 a = *(const float4*)xs;
        float4 b = *(const float4*)(xs + 4);
        ax[0] = (short)f2bf(a.x); ax[1] = (short)f2bf(a.y);
        ax[2] = (short)f2bf(a.z); ax[3] = (short)f2bf(a.w);
        ax[4] = (short)f2bf(b.x); ax[5] = (short)f2bf(b.y);
        ax[6] = (short)f2bf(b.z); ax[7] = (short)f2bf(b.w);
    }

    #pragma unroll
    for (int nt = 0; nt < 4; ++nt) {
        const int nb = w * 64 + nt * 16;
        short8 bf = *(const short8*)(W1t + (size_t)(w * 4 + nt) * 512 + lane * 8);
        floatx4 acc = (floatx4){0.f, 0.f, 0.f, 0.f};
        acc = __builtin_amdgcn_mfma_f32_16x16x32_bf16(ax, bf, acc, 0, 0, 0);
        const float bias = b1[nb + r16];
        #pragma unroll
        for (int reg = 0; reg < 4; ++reg) {
            float h = tanhf(acc[reg] + bias);
            int m = g * 4 + reg;
            int k = nb + r16;
            hB[m][k] = f2bf(h);
            T1[(size_t)(sb >> 4) * 4096 + offFrag256(m, k)] = f2bf(1.0f - h * h);
        }
    }
    __syncthreads();

    short8 bfr[8];
    #pragma unroll
    for (int ks = 0; ks < 8; ++ks)
        bfr[ks] = *(const short8*)&hB[r16][ks * 32 + g * 8];

    const int stile64 = sb >> 6;
    const int mt64    = (sb >> 4) & 3;

    unsigned short h2st[4][4];
    #pragma unroll
    for (int mt = 0; mt < 4; ++mt) {
        const int cb = w * 64 + mt * 16;
        floatx4 acc = (floatx4){0.f, 0.f, 0.f, 0.f};
        #pragma unroll
        for (int ks = 0; ks < 8; ++ks) {
            short8 af = *(const short8*)(W2t + (size_t)((w * 4 + mt) * 8 + ks) * 512 + lane * 8);
            acc = __builtin_amdgcn_mfma_f32_16x16x32_bf16(af, bfr[ks], acc, 0, 0, 0);
        }
        #pragma unroll
        for (int reg = 0; reg < 4; ++reg) {
            const int c2 = cb + g * 4 + reg;
            float h = tanhf(acc[reg] + b2[c2]);
            unsigned short hb = f2bf(h);
            T2[(size_t)stile64 * 16384
               + (size_t)(mt64 * 16 + (c2 >> 4)) * 256
               + ((c2 & 15) + (r16 >> 2) * 16) * 4 + (r16 & 3)] = f2bf(1.0f - h * h);
            if (net)
                H2c[(size_t)(sb >> 4) * 4096 + offFrag256(r16, c2)] = hb;
            h2st[mt][reg] = hb;
        }
    }

    if (!net) {
        __syncthreads();
        #pragma unroll
        for (int mt = 0; mt < 4; ++mt)
            #pragma unroll
            for (int reg = 0; reg < 4; ++reg)
                hB[r16][w * 64 + mt * 16 + g * 4 + reg] = h2st[mt][reg];
        __syncthreads();

        if (w < 2) {
            floatx4 acc = (floatx4){0.f, 0.f, 0.f, 0.f};
            #pragma unroll
            for (int ks = 0; ks < 8; ++ks) {
                short8 af = *(const short8*)(sW3t + (size_t)(w * 8 + ks) * 512 + lane * 8);
                short8 bf = *(const short8*)&hB[r16][ks * 32 + g * 8];
                acc = __builtin_amdgcn_mfma_f32_16x16x32_bf16(af, bf, acc, 0, 0, 0);
            }
            #pragma unroll
            for (int reg = 0; reg < 4; ++reg) {
                const int m = w * 16 + g * 4 + reg;
                out_score[(size_t)(sb + r16) * 32 + m] = acc[reg] + sb3[m];
            }
        }
    }
}

// ============================================================================
// KB v7: 128-row stiles (M doubled) -> B-operand L2 traffic halved, MFMA:VMEM
// ratio doubled. grid (16 stiles, 37 jobs) = 592 blocks, 2+/CU.
// acc[8 mt][4 nt] held (128 VGPR); af[8] reloaded per k-chunk; all loads
// wave-coalesced 1 KB (fragment-linear). LDS only for final reduction.
// ============================================================================
__global__ __launch_bounds__(256, 2) void kb_mfma(
    const unsigned short* __restrict__ T1s, const unsigned short* __restrict__ T2s,
    const unsigned short* __restrict__ T1c, const unsigned short* __restrict__ T2c,
    const unsigned short* __restrict__ H2c,
    const unsigned short* __restrict__ Mt,  const unsigned short* __restrict__ cW3t,
    const float* __restrict__ cb3,
    float* __restrict__ out_trace, float* __restrict__ out_cdiv,
    float* __restrict__ out_cov)
{
    const int stile = blockIdx.x;        // 0..15, 128 rows each
    const int job   = blockIdx.y;        // 0..36
    const int sbase = stile * 128;
    const bool contr = (job < 33);

    const unsigned short* A   = contr ? (job == 0 ? T1s : T1c) : H2c;
    const unsigned short* Bm  = contr ? (Mt + (size_t)job * 65536)
                                      : (cW3t + (size_t)(job - 33) * 65536);
    const unsigned short* T2f = (job == 0) ? T2s : T2c;

    __shared__ float red[4][128];

    const int tid  = threadIdx.x;
    const int w    = tid >> 6;
    const int lane = tid & 63;
    const int g    = lane >> 4;
    const int r16  = lane & 15;
    const int st8  = stile * 8;          // first m-tile index

    floatx4 acc[8][4];
    #pragma unroll
    for (int mt = 0; mt < 8; ++mt)
        #pragma unroll
        for (int nt = 0; nt < 4; ++nt)
            acc[mt][nt] = (floatx4){0.f, 0.f, 0.f, 0.f};

    for (int c = 0; c < 8; ++c) {
        short8 bf[4];
        #pragma unroll
        for (int nt = 0; nt < 4; ++nt)
            bf[nt] = *(const short8*)(Bm + (size_t)((w * 4 + nt) * 8 + c) * 512 + lane * 8);
        short8 af[8];
        #pragma unroll
        for (int mt = 0; mt < 8; ++mt)
            af[mt] = *(const short8*)(A + (size_t)((st8 + mt) * 8 + c) * 512 + lane * 8);
        #pragma unroll
        for (int mt = 0; mt < 8; ++mt)
            #pragma unroll
            for (int nt = 0; nt < 4; ++nt)
                acc[mt][nt] = __builtin_amdgcn_mfma_f32_16x16x32_bf16(af[mt], bf[nt], acc[mt][nt], 0, 0, 0);
    }

    if (contr) {
        float pp[8][4];
        #pragma unroll
        for (int mt = 0; mt < 8; ++mt)
            #pragma unroll
            for (int reg = 0; reg < 4; ++reg) pp[mt][reg] = 0.f;

        #pragma unroll
        for (int mt = 0; mt < 8; ++mt) {
            const int st64 = stile * 2 + (mt >> 2);   // 64-row C-stile
            const int m64  = mt & 3;
            #pragma unroll
            for (int nt = 0; nt < 4; ++nt) {
                ushort4v t2q = *(const ushort4v*)(T2f + (size_t)st64 * 16384
                                 + (size_t)((m64 * 16 + (w * 4 + nt)) * 64 + lane) * 4);
                #pragma unroll
                for (int reg = 0; reg < 4; ++reg)
                    pp[mt][reg] += acc[mt][nt][reg] * bf2f(t2q[reg]);
            }
        }

        #pragma unroll
        for (int mt = 0; mt < 8; ++mt)
            #pragma unroll
            for (int reg = 0; reg < 4; ++reg) {
                float v = pp[mt][reg];
                v += __shfl_xor(v, 1, 64);
                v += __shfl_xor(v, 2, 64);
                v += __shfl_xor(v, 4, 64);
                v += __shfl_xor(v, 8, 64);
                pp[mt][reg] = v;
            }
        if (r16 == 0) {
            #pragma unroll
            for (int mt = 0; mt < 8; ++mt)
                #pragma unroll
                for (int reg = 0; reg < 4; ++reg)
                    red[w][mt * 16 + g * 4 + reg] = pp[mt][reg];
        }
        __syncthreads();
        if (tid < 128) {
            float v = red[0][tid] + red[1][tid] + red[2][tid] + red[3][tid];
            int sg = sbase + tid;
            if (job == 0) out_trace[sg] = v;
            else          out_cdiv[(size_t)sg * Dd + (job - 1)] = v;
        }
    } else {
        const int n0 = (job - 33) * 256;
        #pragma unroll
        for (int mt = 0; mt < 8; ++mt)
            #pragma unroll
            for (int nt = 0; nt < 4; ++nt) {
                const int n = (w * 4 + nt) * 16 + r16;
                const float bias = cb3[n0 + n];
                #pragma unroll
                for (int reg = 0; reg < 4; ++reg) {
                    const int r = mt * 16 + g * 4 + reg;
                    out_cov[(size_t)(sbase + r) * 1024 + n0 + n] = acc[mt][nt][reg] + bias;
                }
            }
    }
}

// ============================================================================
extern "C" void kernel_launch(void* const* d_in, const int* in_sizes, int n_in,
                              void* d_out, int out_size, void* d_ws, size_t ws_size,
                              hipStream_t stream) {
    const float* x   = (const float*)d_in[0];
    const float* sW1 = (const float*)d_in[1];
    const float* sb1 = (const float*)d_in[2];
    const float* sW2 = (const float*)d_in[3];
    const float* sb2 = (const float*)d_in[4];
    const float* sW3 = (const float*)d_in[5];
    const float* sb3 = (const float*)d_in[6];
    const float* cW1 = (const float*)d_in[7];
    const float* cb1 = (const float*)d_in[8];
    const float* cW2 = (const float*)d_in[9];
    const float* cb2 = (const float*)d_in[10];
    const float* cW3 = (const float*)d_in[11];
    const float* cb3 = (const float*)d_in[12];

    const int B = in_sizes[0] / Dd;   // 2048

    float* out       = (float*)d_out;
    float* out_score = out;                                  // [B,32]
    float* out_trace = out + (size_t)B * Dd;                 // [B]
    float* out_cov   = out_trace + B;                        // [B,32,32]
    float* out_cdiv  = out_cov + (size_t)B * Dd * Dd;        // [B,32]

    unsigned short* ws16 = (unsigned short*)d_ws;
    const size_t SZ = (size_t)B * 256;
    unsigned short* T1s  = ws16;                             // A-frag
    unsigned short* T2s  = ws16 + SZ;                        // C-frag
    unsigned short* T1c  = ws16 + 2 * SZ;
    unsigned short* T2c  = ws16 + 3 * SZ;
    unsigned short* H2c  = ws16 + 4 * SZ;
    unsigned short* Mt   = ws16 + 5 * SZ;                    // [33] B-frag
    unsigned short* cW3t = Mt + (size_t)33 * 65536;          // B-frag
    unsigned short* sW2t = cW3t + (size_t)1024 * 256;        // A-frag
    unsigned short* cW2t = sW2t + (size_t)256 * 256;
    unsigned short* sW3t = cW2t + (size_t)256 * 256;         // A-frag [32 rows]
    unsigned short* W1ts = sW3t + (size_t)32 * 256;          // B-frag K=32
    unsigned short* W1tc = W1ts + (size_t)256 * 32;

    k1_prep<<<dim3(51), dim3(256), 0, stream>>>(
        sW1, sW2, sW3, cW1, cW2, cW3,
        cW3t, sW2t, cW2t, sW3t, W1ts, W1tc);

    ka_mfma<<<dim3(256 + 132), dim3(256), 0, stream>>>(
        x, sW1, sW2, sW3, cW1, cW2, cW3,
        W1ts, W1tc, sW2t, cW2t, sW3t,
        sb1, sb2, sb3, cb1, cb2,
        out_score, T1s, T2s, T1c, T2c, H2c, Mt);

    kb_mfma<<<dim3(16, 37), dim3(256), 0, stream>>>(
        T1s, T2s, T1c, T2c, H2c, Mt, cW3t, cb3,
        out_trace, out_cdiv, out_cov);
}

// Round 12
// 121.459 us; speedup vs baseline: 1.0944x; 1.0944x over previous
//
#include <hip/hip_runtime.h>
#include <math.h>

#define Dd 32
#define Hh 256

using short8   = __attribute__((ext_vector_type(8))) short;
using floatx4  = __attribute__((ext_vector_type(4))) float;
typedef unsigned short ushort4v __attribute__((ext_vector_type(4)));

__device__ inline unsigned short f2bf(float f) {
    union { float f; unsigned u; } v; v.f = f;
    unsigned r = (v.u + 0x7FFFu + ((v.u >> 16) & 1u)) >> 16;
    return (unsigned short)r;
}
__device__ inline float bf2f(unsigned short h) {
    union { unsigned u; float f; } v; v.u = ((unsigned)h) << 16;
    return v.f;
}

// Fragment-linear layouts (16x16x32 MFMA) — see R9.
__device__ inline size_t offFrag256(int row, int k) {
    return ((size_t)((row >> 4) * 8 + (k >> 5))) * 512
         + (((k & 31) >> 3) * 16 + (row & 15)) * 8 + (k & 7);
}

// ============================================================================
// K1: weight transposes to bf16 FRAGMENT layout. grid 51 blocks. (R9 identical)
// ============================================================================
__global__ __launch_bounds__(256) void k1_prep(
    const float* __restrict__ sW1, const float* __restrict__ sW2, const float* __restrict__ sW3,
    const float* __restrict__ cW1, const float* __restrict__ cW2, const float* __restrict__ cW3,
    unsigned short* __restrict__ cW3t,
    unsigned short* __restrict__ sW2t, unsigned short* __restrict__ cW2t,
    unsigned short* __restrict__ sW3t,
    unsigned short* __restrict__ W1ts, unsigned short* __restrict__ W1tc)
{
    __shared__ float fl[64][33];
    const int tid = threadIdx.x;
    const int bid = blockIdx.x;

    if (bid < 49) {
        const float* src; unsigned short* dst; int stride, n0;
        if (bid < 32)      { src = cW3; dst = cW3t; stride = 1024; n0 = bid * 32; }
        else if (bid < 40) { src = sW2; dst = sW2t; stride = 256;  n0 = (bid - 32) * 32; }
        else if (bid < 48) { src = cW2; dst = cW2t; stride = 256;  n0 = (bid - 40) * 32; }
        else               { src = sW3; dst = sW3t; stride = 32;   n0 = 0; }

        const int nn  = tid & 31, kg = tid >> 5;
        const int nn2 = tid >> 3, ks = (tid & 7) * 8;

        for (int p = 0; p < 4; ++p) {
            if (p) __syncthreads();
            #pragma unroll
            for (int j = 0; j < 8; ++j) {
                int kk = kg * 8 + j;
                fl[kk][nn] = src[(size_t)(p * 64 + kk) * stride + n0 + nn];
            }
            __syncthreads();
            short8 v;
            #pragma unroll
            for (int j = 0; j < 8; ++j) v[j] = (short)f2bf(fl[ks + j][nn2]);
            *(short8*)(dst + offFrag256(n0 + nn2, p * 64 + ks)) = v;
        }
        return;
    }
    {
        const float* W1 = (bid == 49) ? sW1 : cW1;
        unsigned short* dst = (bid == 49) ? W1ts : W1tc;
        const int n = tid;
        #pragma unroll
        for (int c8 = 0; c8 < 4; ++c8) {
            short8 v;
            #pragma unroll
            for (int j = 0; j < 8; ++j)
                v[j] = (short)f2bf(W1[(size_t)(c8 * 8 + j) * 256 + n]);
            *(short8*)(dst + (size_t)(n >> 4) * 512 + (c8 * 16 + (n & 15)) * 8) = v;
        }
    }
}

// ============================================================================
// KA: forward MFMA (256 blocks) + Mt precompute (132 blocks). grid 388.
// R12 change: Mt partition's C3 slice is LDS-staged with coalesced reads
// (was: 4 KB-strided per-lane reads = 64 cache lines per wave instruction).
// ============================================================================
__global__ __launch_bounds__(256) void ka_mfma(
    const float* __restrict__ x,
    const float* __restrict__ sW1, const float* __restrict__ sW2, const float* __restrict__ sW3,
    const float* __restrict__ cW1, const float* __restrict__ cW2, const float* __restrict__ cW3,
    const unsigned short* __restrict__ W1ts, const unsigned short* __restrict__ W1tc,
    const unsigned short* __restrict__ sW2t, const unsigned short* __restrict__ cW2t,
    const unsigned short* __restrict__ sW3t,
    const float* __restrict__ sb1, const float* __restrict__ sb2, const float* __restrict__ sb3,
    const float* __restrict__ cb1, const float* __restrict__ cb2,
    float* __restrict__ out_score,
    unsigned short* __restrict__ T1s, unsigned short* __restrict__ T2s,
    unsigned short* __restrict__ T1c, unsigned short* __restrict__ T2c,
    unsigned short* __restrict__ H2c, unsigned short* __restrict__ Mt)
{
    __shared__ char smem[43008];
    const int tid = threadIdx.x;
    const int bid = blockIdx.x;

    if (bid >= 256) {
        // ---------------- Mt precompute (coalesced ct via LDS) ----------------
        const int pb = bid - 256;
        const int kq = pb & 3;
        const int i  = pb >> 2;
        float (*W1t)[36] = (float(*)[36])smem;              // [64][36] = 9216 B
        float (*ctS)[33] = (float(*)[33])(smem + 9216);     // [256][33] = 33792 B

        const float *W1, *W2, *C3;
        int cstride, coff;
        if (i == 0) { W1 = sW1; W2 = sW2; C3 = sW3; cstride = 32;   coff = 0; }
        else        { W1 = cW1; W2 = cW2; C3 = cW3; cstride = 1024; coff = (i - 1) * 32; }

        {
            int kl = tid & 63, jg = tid >> 6;
            #pragma unroll
            for (int jj = 0; jj < 8; ++jj) {
                int j = jg * 8 + jj;
                W1t[kl][j] = W1[j * 256 + kq * 64 + kl];
            }
        }
        // coalesced stage: wave covers 2 rows x 32 contiguous floats
        {
            const int row0 = tid >> 5, col = tid & 31;
            #pragma unroll
            for (int p8 = 0; p8 < 32; ++p8) {
                int row = p8 * 8 + row0;
                ctS[row][col] = C3[(size_t)row * cstride + coff + col];
            }
        }
        __syncthreads();

        float ct[32];
        #pragma unroll
        for (int j = 0; j < 32; ++j) ct[j] = ctS[tid][j];   // stride-33: 2-way alias, free

        for (int kg = 0; kg < 8; ++kg) {
            const int kbase = kq * 64 + kg * 8;
            short8 pk;
            #pragma unroll
            for (int q = 0; q < 8; ++q) {
                float a = 0.f;
                #pragma unroll
                for (int j4 = 0; j4 < 8; ++j4) {
                    float4 w = *(const float4*)&W1t[kg * 8 + q][j4 * 4];
                    a += w.x * ct[j4 * 4 + 0] + w.y * ct[j4 * 4 + 1]
                       + w.z * ct[j4 * 4 + 2] + w.w * ct[j4 * 4 + 3];
                }
                float m = a * W2[(size_t)(kbase + q) * 256 + tid];
                pk[q] = (short)f2bf(m);
            }
            *(short8*)(Mt + (size_t)i * 65536 + offFrag256(tid, kbase)) = pk;
        }
        return;
    }

    // ---------------- forward (R9 identical) ----------------
    const int net = bid & 1;
    const int sb  = (bid >> 1) * 16;

    const unsigned short* W1t = net ? W1tc : W1ts;
    const unsigned short* W2t = net ? cW2t : sW2t;
    const float* b1 = net ? cb1 : sb1;
    const float* b2 = net ? cb2 : sb2;
    unsigned short* T1 = net ? T1c : T1s;
    unsigned short* T2 = net ? T2c : T2s;

    unsigned short (*hB)[264] = (unsigned short(*)[264])smem;

    const int w    = tid >> 6;
    const int lane = tid & 63;
    const int g    = lane >> 4;
    const int r16  = lane & 15;

    short8 ax;
    {
        const float* xs = x + (size_t)(sb + r16) * 32 + g * 8;
        float4 a = *(const float4*)xs;
        float4 b = *(const float4*)(xs + 4);
        ax[0] = (short)f2bf(a.x); ax[1] = (short)f2bf(a.y);
        ax[2] = (short)f2bf(a.z); ax[3] = (short)f2bf(a.w);
        ax[4] = (short)f2bf(b.x); ax[5] = (short)f2bf(b.y);
        ax[6] = (short)f2bf(b.z); ax[7] = (short)f2bf(b.w);
    }

    #pragma unroll
    for (int nt = 0; nt < 4; ++nt) {
        const int nb = w * 64 + nt * 16;
        short8 bf = *(const short8*)(W1t + (size_t)(w * 4 + nt) * 512 + lane * 8);
        floatx4 acc = (floatx4){0.f, 0.f, 0.f, 0.f};
        acc = __builtin_amdgcn_mfma_f32_16x16x32_bf16(ax, bf, acc, 0, 0, 0);
        const float bias = b1[nb + r16];
        #pragma unroll
        for (int reg = 0; reg < 4; ++reg) {
            float h = tanhf(acc[reg] + bias);
            int m = g * 4 + reg;
            int k = nb + r16;
            hB[m][k] = f2bf(h);
            T1[(size_t)(sb >> 4) * 4096 + offFrag256(m, k)] = f2bf(1.0f - h * h);
        }
    }
    __syncthreads();

    short8 bfr[8];
    #pragma unroll
    for (int ks = 0; ks < 8; ++ks)
        bfr[ks] = *(const short8*)&hB[r16][ks * 32 + g * 8];

    const int stile64 = sb >> 6;
    const int mt64    = (sb >> 4) & 3;

    unsigned short h2st[4][4];
    #pragma unroll
    for (int mt = 0; mt < 4; ++mt) {
        const int cb = w * 64 + mt * 16;
        floatx4 acc = (floatx4){0.f, 0.f, 0.f, 0.f};
        #pragma unroll
        for (int ks = 0; ks < 8; ++ks) {
            short8 af = *(const short8*)(W2t + (size_t)((w * 4 + mt) * 8 + ks) * 512 + lane * 8);
            acc = __builtin_amdgcn_mfma_f32_16x16x32_bf16(af, bfr[ks], acc, 0, 0, 0);
        }
        #pragma unroll
        for (int reg = 0; reg < 4; ++reg) {
            const int c2 = cb + g * 4 + reg;
            float h = tanhf(acc[reg] + b2[c2]);
            unsigned short hb = f2bf(h);
            T2[(size_t)stile64 * 16384
               + (size_t)(mt64 * 16 + (c2 >> 4)) * 256
               + ((c2 & 15) + (r16 >> 2) * 16) * 4 + (r16 & 3)] = f2bf(1.0f - h * h);
            if (net)
                H2c[(size_t)(sb >> 4) * 4096 + offFrag256(r16, c2)] = hb;
            h2st[mt][reg] = hb;
        }
    }

    if (!net) {
        __syncthreads();
        #pragma unroll
        for (int mt = 0; mt < 4; ++mt)
            #pragma unroll
            for (int reg = 0; reg < 4; ++reg)
                hB[r16][w * 64 + mt * 16 + g * 4 + reg] = h2st[mt][reg];
        __syncthreads();

        if (w < 2) {
            floatx4 acc = (floatx4){0.f, 0.f, 0.f, 0.f};
            #pragma unroll
            for (int ks = 0; ks < 8; ++ks) {
                short8 af = *(const short8*)(sW3t + (size_t)(w * 8 + ks) * 512 + lane * 8);
                short8 bf = *(const short8*)&hB[r16][ks * 32 + g * 8];
                acc = __builtin_amdgcn_mfma_f32_16x16x32_bf16(af, bf, acc, 0, 0, 0);
            }
            #pragma unroll
            for (int reg = 0; reg < 4; ++reg) {
                const int m = w * 16 + g * 4 + reg;
                out_score[(size_t)(sb + r16) * 32 + m] = acc[reg] + sb3[m];
            }
        }
    }
}

// ============================================================================
// KB v6 (exact R9 revert): LDS-free, barrier-free register GEMM; all loads
// wave-coalesced 1 KB. grid (32 stiles, 37 jobs), 256 thr, 4 waves.
// ============================================================================
__global__ __launch_bounds__(256, 3) void kb_mfma(
    const unsigned short* __restrict__ T1s, const unsigned short* __restrict__ T2s,
    const unsigned short* __restrict__ T1c, const unsigned short* __restrict__ T2c,
    const unsigned short* __restrict__ H2c,
    const unsigned short* __restrict__ Mt,  const unsigned short* __restrict__ cW3t,
    const float* __restrict__ cb3,
    float* __restrict__ out_trace, float* __restrict__ out_cdiv,
    float* __restrict__ out_cov)
{
    const int stile = blockIdx.x;
    const int job   = blockIdx.y;
    const int sbase = stile * 64;
    const bool contr = (job < 33);

    const unsigned short* A   = contr ? (job == 0 ? T1s : T1c) : H2c;
    const unsigned short* Bm  = contr ? (Mt + (size_t)job * 65536)
                                      : (cW3t + (size_t)(job - 33) * 65536);
    const unsigned short* T2f = (job == 0) ? T2s : T2c;

    __shared__ float red[4][64];

    const int tid  = threadIdx.x;
    const int w    = tid >> 6;
    const int lane = tid & 63;
    const int g    = lane >> 4;
    const int r16  = lane & 15;
    const int st4  = stile * 4;

    floatx4 acc[4][4];
    #pragma unroll
    for (int mt = 0; mt < 4; ++mt)
        #pragma unroll
        for (int nt = 0; nt < 4; ++nt)
            acc[mt][nt] = (floatx4){0.f, 0.f, 0.f, 0.f};

    #pragma unroll
    for (int c = 0; c < 8; ++c) {
        short8 af[4], bf[4];
        #pragma unroll
        for (int mt = 0; mt < 4; ++mt)
            af[mt] = *(const short8*)(A + (size_t)((st4 + mt) * 8 + c) * 512 + lane * 8);
        #pragma unroll
        for (int nt = 0; nt < 4; ++nt)
            bf[nt] = *(const short8*)(Bm + (size_t)((w * 4 + nt) * 8 + c) * 512 + lane * 8);
        #pragma unroll
        for (int mt = 0; mt < 4; ++mt)
            #pragma unroll
            for (int nt = 0; nt < 4; ++nt)
                acc[mt][nt] = __builtin_amdgcn_mfma_f32_16x16x32_bf16(af[mt], bf[nt], acc[mt][nt], 0, 0, 0);
    }

    if (contr) {
        float pp[4][4];
        #pragma unroll
        for (int mt = 0; mt < 4; ++mt)
            #pragma unroll
            for (int reg = 0; reg < 4; ++reg) pp[mt][reg] = 0.f;

        #pragma unroll
        for (int mt = 0; mt < 4; ++mt)
            #pragma unroll
            for (int nt = 0; nt < 4; ++nt) {
                ushort4v t2q = *(const ushort4v*)(T2f + (size_t)stile * 16384
                                 + (size_t)((mt * 16 + (w * 4 + nt)) * 64 + lane) * 4);
                #pragma unroll
                for (int reg = 0; reg < 4; ++reg)
                    pp[mt][reg] += acc[mt][nt][reg] * bf2f(t2q[reg]);
            }

        #pragma unroll
        for (int mt = 0; mt < 4; ++mt)
            #pragma unroll
            for (int reg = 0; reg < 4; ++reg) {
                float v = pp[mt][reg];
                v += __shfl_xor(v, 1, 64);
                v += __shfl_xor(v, 2, 64);
                v += __shfl_xor(v, 4, 64);
                v += __shfl_xor(v, 8, 64);
                pp[mt][reg] = v;
            }
        if (r16 == 0) {
            #pragma unroll
            for (int mt = 0; mt < 4; ++mt)
                #pragma unroll
                for (int reg = 0; reg < 4; ++reg)
                    red[w][mt * 16 + g * 4 + reg] = pp[mt][reg];
        }
        __syncthreads();
        if (tid < 64) {
            float v = red[0][tid] + red[1][tid] + red[2][tid] + red[3][tid];
            int sg = sbase + tid;
            if (job == 0) out_trace[sg] = v;
            else          out_cdiv[(size_t)sg * Dd + (job - 1)] = v;
        }
    } else {
        const int n0 = (job - 33) * 256;
        #pragma unroll
        for (int mt = 0; mt < 4; ++mt)
            #pragma unroll
            for (int nt = 0; nt < 4; ++nt) {
                const int n = (w * 4 + nt) * 16 + r16;
                const float bias = cb3[n0 + n];
                #pragma unroll
                for (int reg = 0; reg < 4; ++reg) {
                    const int r = mt * 16 + g * 4 + reg;
                    out_cov[(size_t)(sbase + r) * 1024 + n0 + n] = acc[mt][nt][reg] + bias;
                }
            }
    }
}

// ============================================================================
extern "C" void kernel_launch(void* const* d_in, const int* in_sizes, int n_in,
                              void* d_out, int out_size, void* d_ws, size_t ws_size,
                              hipStream_t stream) {
    const float* x   = (const float*)d_in[0];
    const float* sW1 = (const float*)d_in[1];
    const float* sb1 = (const float*)d_in[2];
    const float* sW2 = (const float*)d_in[3];
    const float* sb2 = (const float*)d_in[4];
    const float* sW3 = (const float*)d_in[5];
    const float* sb3 = (const float*)d_in[6];
    const float* cW1 = (const float*)d_in[7];
    const float* cb1 = (const float*)d_in[8];
    const float* cW2 = (const float*)d_in[9];
    const float* cb2 = (const float*)d_in[10];
    const float* cW3 = (const float*)d_in[11];
    const float* cb3 = (const float*)d_in[12];

    const int B = in_sizes[0] / Dd;   // 2048

    float* out       = (float*)d_out;
    float* out_score = out;                                  // [B,32]
    float* out_trace = out + (size_t)B * Dd;                 // [B]
    float* out_cov   = out_trace + B;                        // [B,32,32]
    float* out_cdiv  = out_cov + (size_t)B * Dd * Dd;        // [B,32]

    unsigned short* ws16 = (unsigned short*)d_ws;
    const size_t SZ = (size_t)B * 256;
    unsigned short* T1s  = ws16;                             // A-frag
    unsigned short* T2s  = ws16 + SZ;                        // C-frag
    unsigned short* T1c  = ws16 + 2 * SZ;
    unsigned short* T2c  = ws16 + 3 * SZ;
    unsigned short* H2c  = ws16 + 4 * SZ;
    unsigned short* Mt   = ws16 + 5 * SZ;                    // [33] B-frag
    unsigned short* cW3t = Mt + (size_t)33 * 65536;          // B-frag
    unsigned short* sW2t = cW3t + (size_t)1024 * 256;        // A-frag
    unsigned short* cW2t = sW2t + (size_t)256 * 256;
    unsigned short* sW3t = cW2t + (size_t)256 * 256;         // A-frag [32 rows]
    unsigned short* W1ts = sW3t + (size_t)32 * 256;          // B-frag K=32
    unsigned short* W1tc = W1ts + (size_t)256 * 32;

    k1_prep<<<dim3(51), dim3(256), 0, stream>>>(
        sW1, sW2, sW3, cW1, cW2, cW3,
        cW3t, sW2t, cW2t, sW3t, W1ts, W1tc);

    ka_mfma<<<dim3(256 + 132), dim3(256), 0, stream>>>(
        x, sW1, sW2, sW3, cW1, cW2, cW3,
        W1ts, W1tc, sW2t, cW2t, sW3t,
        sb1, sb2, sb3, cb1, cb2,
        out_score, T1s, T2s, T1c, T2c, H2c, Mt);

    kb_mfma<<<dim3(B / 64, 37), dim3(256), 0, stream>>>(
        T1s, T2s, T1c, T2c, H2c, Mt, cW3t, cb3,
        out_trace, out_cdiv, out_cov);
}

// Round 13
// 113.287 us; speedup vs baseline: 1.1734x; 1.0721x over previous
//
#include <hip/hip_runtime.h>
#include <math.h>

#define Dd 32
#define Hh 256

using short8   = __attribute__((ext_vector_type(8))) short;
using floatx4  = __attribute__((ext_vector_type(4))) float;
typedef unsigned short ushort4v __attribute__((ext_vector_type(4)));

__device__ inline unsigned short f2bf(float f) {
    union { float f; unsigned u; } v; v.f = f;
    unsigned r = (v.u + 0x7FFFu + ((v.u >> 16) & 1u)) >> 16;
    return (unsigned short)r;
}
__device__ inline float bf2f(unsigned short h) {
    union { unsigned u; float f; } v; v.u = ((unsigned)h) << 16;
    return v.f;
}
// fast tanh: 1 - 2/(e^{2z}+1). |err| ~1e-6 << bf16 rounding (4e-3).
// Saturates correctly: z->+inf: exp->inf, rcp->0, h=1; z->-inf: exp->0, h=-1.
__device__ inline float fast_tanh(float z) {
    float e = __expf(2.0f * z);
    return 1.0f - 2.0f * __builtin_amdgcn_rcpf(e + 1.0f);
}

// Fragment-linear layouts (16x16x32 MFMA) — see R9.
__device__ inline size_t offFrag256(int row, int k) {
    return ((size_t)((row >> 4) * 8 + (k >> 5))) * 512
         + (((k & 31) >> 3) * 16 + (row & 15)) * 8 + (k & 7);
}

// ============================================================================
// K1: weight transposes to bf16 FRAGMENT layout. grid 51 blocks. (R9 identical)
// ============================================================================
__global__ __launch_bounds__(256) void k1_prep(
    const float* __restrict__ sW1, const float* __restrict__ sW2, const float* __restrict__ sW3,
    const float* __restrict__ cW1, const float* __restrict__ cW2, const float* __restrict__ cW3,
    unsigned short* __restrict__ cW3t,
    unsigned short* __restrict__ sW2t, unsigned short* __restrict__ cW2t,
    unsigned short* __restrict__ sW3t,
    unsigned short* __restrict__ W1ts, unsigned short* __restrict__ W1tc)
{
    __shared__ float fl[64][33];
    const int tid = threadIdx.x;
    const int bid = blockIdx.x;

    if (bid < 49) {
        const float* src; unsigned short* dst; int stride, n0;
        if (bid < 32)      { src = cW3; dst = cW3t; stride = 1024; n0 = bid * 32; }
        else if (bid < 40) { src = sW2; dst = sW2t; stride = 256;  n0 = (bid - 32) * 32; }
        else if (bid < 48) { src = cW2; dst = cW2t; stride = 256;  n0 = (bid - 40) * 32; }
        else               { src = sW3; dst = sW3t; stride = 32;   n0 = 0; }

        const int nn  = tid & 31, kg = tid >> 5;
        const int nn2 = tid >> 3, ks = (tid & 7) * 8;

        for (int p = 0; p < 4; ++p) {
            if (p) __syncthreads();
            #pragma unroll
            for (int j = 0; j < 8; ++j) {
                int kk = kg * 8 + j;
                fl[kk][nn] = src[(size_t)(p * 64 + kk) * stride + n0 + nn];
            }
            __syncthreads();
            short8 v;
            #pragma unroll
            for (int j = 0; j < 8; ++j) v[j] = (short)f2bf(fl[ks + j][nn2]);
            *(short8*)(dst + offFrag256(n0 + nn2, p * 64 + ks)) = v;
        }
        return;
    }
    {
        const float* W1 = (bid == 49) ? sW1 : cW1;
        unsigned short* dst = (bid == 49) ? W1ts : W1tc;
        const int n = tid;
        #pragma unroll
        for (int c8 = 0; c8 < 4; ++c8) {
            short8 v;
            #pragma unroll
            for (int j = 0; j < 8; ++j)
                v[j] = (short)f2bf(W1[(size_t)(c8 * 8 + j) * 256 + n]);
            *(short8*)(dst + (size_t)(n >> 4) * 512 + (c8 * 16 + (n & 15)) * 8) = v;
        }
    }
}

// ============================================================================
// KA v2: 512-thread blocks (8 waves). grid 388 = 256 forward + 132 Mt.
// Forward: 16 samples x net per block; N-dim split across 8 waves (wave w
// owns cols [w*32, w*32+32) in both layers) -> 8+ waves/CU for latency hiding
// (was 4 at 1 block/CU). fast_tanh replaces libm tanhf.
// Mt: kg-loop split across thread halves; ct LDS-staged coalesced (R12).
// ============================================================================
__global__ __launch_bounds__(512, 2) void ka_mfma(
    const float* __restrict__ x,
    const float* __restrict__ sW1, const float* __restrict__ sW2, const float* __restrict__ sW3,
    const float* __restrict__ cW1, const float* __restrict__ cW2, const float* __restrict__ cW3,
    const unsigned short* __restrict__ W1ts, const unsigned short* __restrict__ W1tc,
    const unsigned short* __restrict__ sW2t, const unsigned short* __restrict__ cW2t,
    const unsigned short* __restrict__ sW3t,
    const float* __restrict__ sb1, const float* __restrict__ sb2, const float* __restrict__ sb3,
    const float* __restrict__ cb1, const float* __restrict__ cb2,
    float* __restrict__ out_score,
    unsigned short* __restrict__ T1s, unsigned short* __restrict__ T2s,
    unsigned short* __restrict__ T1c, unsigned short* __restrict__ T2c,
    unsigned short* __restrict__ H2c, unsigned short* __restrict__ Mt)
{
    __shared__ char smem[43008];
    const int tid = threadIdx.x;
    const int bid = blockIdx.x;

    if (bid >= 256) {
        // ---------------- Mt precompute (512 threads, kg split) ----------------
        const int pb = bid - 256;
        const int kq = pb & 3;
        const int i  = pb >> 2;
        float (*W1t)[36] = (float(*)[36])smem;              // [64][36]
        float (*ctS)[33] = (float(*)[33])(smem + 9216);     // [256][33]

        const float *W1, *W2, *C3;
        int cstride, coff;
        if (i == 0) { W1 = sW1; W2 = sW2; C3 = sW3; cstride = 32;   coff = 0; }
        else        { W1 = cW1; W2 = cW2; C3 = cW3; cstride = 1024; coff = (i - 1) * 32; }

        {
            int kl = tid & 63, jg = tid >> 6;   // jg 0..7
            #pragma unroll
            for (int jj = 0; jj < 4; ++jj) {
                int j = jg * 4 + jj;
                W1t[kl][j] = W1[j * 256 + kq * 64 + kl];
            }
        }
        {
            const int row0 = tid >> 5, col = tid & 31;   // row0 0..15
            #pragma unroll
            for (int p8 = 0; p8 < 16; ++p8) {
                int row = p8 * 16 + row0;
                ctS[row][col] = C3[(size_t)row * cstride + coff + col];
            }
        }
        __syncthreads();

        const int t     = tid & 255;
        const int khalf = tid >> 8;
        float ct[32];
        #pragma unroll
        for (int j = 0; j < 32; ++j) ct[j] = ctS[t][j];

        for (int kg = khalf * 4; kg < khalf * 4 + 4; ++kg) {
            const int kbase = kq * 64 + kg * 8;
            short8 pk;
            #pragma unroll
            for (int q = 0; q < 8; ++q) {
                float a = 0.f;
                #pragma unroll
                for (int j4 = 0; j4 < 8; ++j4) {
                    float4 w = *(const float4*)&W1t[kg * 8 + q][j4 * 4];
                    a += w.x * ct[j4 * 4 + 0] + w.y * ct[j4 * 4 + 1]
                       + w.z * ct[j4 * 4 + 2] + w.w * ct[j4 * 4 + 3];
                }
                float m = a * W2[(size_t)(kbase + q) * 256 + t];
                pk[q] = (short)f2bf(m);
            }
            *(short8*)(Mt + (size_t)i * 65536 + offFrag256(t, kbase)) = pk;
        }
        return;
    }

    // ---------------- forward: 8 waves, wave w owns cols [w*32, w*32+32) ----
    const int net = bid & 1;
    const int sb  = (bid >> 1) * 16;

    const unsigned short* W1t = net ? W1tc : W1ts;
    const unsigned short* W2t = net ? cW2t : sW2t;
    const float* b1 = net ? cb1 : sb1;
    const float* b2 = net ? cb2 : sb2;
    unsigned short* T1 = net ? T1c : T1s;
    unsigned short* T2 = net ? T2c : T2s;

    unsigned short (*hB)[264] = (unsigned short(*)[264])smem;   // [16][264]

    const int w    = tid >> 6;          // 0..7
    const int lane = tid & 63;
    const int g    = lane >> 4;
    const int r16  = lane & 15;

    short8 ax;
    {
        const float* xs = x + (size_t)(sb + r16) * 32 + g * 8;
        float4 a = *(const float4*)xs;
        float4 b = *(const float4*)(xs + 4);
        ax[0] = (short)f2bf(a.x); ax[1] = (short)f2bf(a.y);
        ax[2] = (short)f2bf(a.z); ax[3] = (short)f2bf(a.w);
        ax[4] = (short)f2bf(b.x); ax[5] = (short)f2bf(b.y);
        ax[6] = (short)f2bf(b.z); ax[7] = (short)f2bf(b.w);
    }

    // layer 1: 2 tiles per wave
    #pragma unroll
    for (int nt = 0; nt < 2; ++nt) {
        const int ti = w * 2 + nt;                // tile 0..15
        const int nb = ti * 16;
        short8 bf = *(const short8*)(W1t + (size_t)ti * 512 + lane * 8);
        floatx4 acc = (floatx4){0.f, 0.f, 0.f, 0.f};
        acc = __builtin_amdgcn_mfma_f32_16x16x32_bf16(ax, bf, acc, 0, 0, 0);
        const float bias = b1[nb + r16];
        #pragma unroll
        for (int reg = 0; reg < 4; ++reg) {
            float h = fast_tanh(acc[reg] + bias);
            int m = g * 4 + reg;
            int k = nb + r16;
            hB[m][k] = f2bf(h);
            T1[(size_t)(sb >> 4) * 4096 + offFrag256(m, k)] = f2bf(1.0f - h * h);
        }
    }
    __syncthreads();

    short8 bfr[8];
    #pragma unroll
    for (int ks = 0; ks < 8; ++ks)
        bfr[ks] = *(const short8*)&hB[r16][ks * 32 + g * 8];

    const int stile64 = sb >> 6;
    const int mt64    = (sb >> 4) & 3;

    unsigned short h2st[2][4];
    #pragma unroll
    for (int mt = 0; mt < 2; ++mt) {
        const int ti = w * 2 + mt;
        const int cb = ti * 16;
        floatx4 acc = (floatx4){0.f, 0.f, 0.f, 0.f};
        #pragma unroll
        for (int ks = 0; ks < 8; ++ks) {
            short8 af = *(const short8*)(W2t + (size_t)(ti * 8 + ks) * 512 + lane * 8);
            acc = __builtin_amdgcn_mfma_f32_16x16x32_bf16(af, bfr[ks], acc, 0, 0, 0);
        }
        #pragma unroll
        for (int reg = 0; reg < 4; ++reg) {
            const int c2 = cb + g * 4 + reg;
            float h = fast_tanh(acc[reg] + b2[c2]);
            unsigned short hb = f2bf(h);
            T2[(size_t)stile64 * 16384
               + (size_t)(mt64 * 16 + (c2 >> 4)) * 256
               + ((c2 & 15) + (r16 >> 2) * 16) * 4 + (r16 & 3)] = f2bf(1.0f - h * h);
            if (net)
                H2c[(size_t)(sb >> 4) * 4096 + offFrag256(r16, c2)] = hb;
            h2st[mt][reg] = hb;
        }
    }

    if (!net) {
        __syncthreads();    // all hB (h1) reads done before overwrite
        #pragma unroll
        for (int mt = 0; mt < 2; ++mt)
            #pragma unroll
            for (int reg = 0; reg < 4; ++reg)
                hB[r16][(w * 2 + mt) * 16 + g * 4 + reg] = h2st[mt][reg];
        __syncthreads();

        if (w < 2) {
            floatx4 acc = (floatx4){0.f, 0.f, 0.f, 0.f};
            #pragma unroll
            for (int ks = 0; ks < 8; ++ks) {
                short8 af = *(const short8*)(sW3t + (size_t)(w * 8 + ks) * 512 + lane * 8);
                short8 bf = *(const short8*)&hB[r16][ks * 32 + g * 8];
                acc = __builtin_amdgcn_mfma_f32_16x16x32_bf16(af, bf, acc, 0, 0, 0);
            }
            #pragma unroll
            for (int reg = 0; reg < 4; ++reg) {
                const int m = w * 16 + g * 4 + reg;
                out_score[(size_t)(sb + r16) * 32 + m] = acc[reg] + sb3[m];
            }
        }
    }
}

// ============================================================================
// KB v6 (R9/R12 identical): LDS-free, barrier-free register GEMM; all loads
// wave-coalesced 1 KB. grid (32 stiles, 37 jobs), 256 thr, 4 waves.
// ============================================================================
__global__ __launch_bounds__(256, 3) void kb_mfma(
    const unsigned short* __restrict__ T1s, const unsigned short* __restrict__ T2s,
    const unsigned short* __restrict__ T1c, const unsigned short* __restrict__ T2c,
    const unsigned short* __restrict__ H2c,
    const unsigned short* __restrict__ Mt,  const unsigned short* __restrict__ cW3t,
    const float* __restrict__ cb3,
    float* __restrict__ out_trace, float* __restrict__ out_cdiv,
    float* __restrict__ out_cov)
{
    const int stile = blockIdx.x;
    const int job   = blockIdx.y;
    const int sbase = stile * 64;
    const bool contr = (job < 33);

    const unsigned short* A   = contr ? (job == 0 ? T1s : T1c) : H2c;
    const unsigned short* Bm  = contr ? (Mt + (size_t)job * 65536)
                                      : (cW3t + (size_t)(job - 33) * 65536);
    const unsigned short* T2f = (job == 0) ? T2s : T2c;

    __shared__ float red[4][64];

    const int tid  = threadIdx.x;
    const int w    = tid >> 6;
    const int lane = tid & 63;
    const int g    = lane >> 4;
    const int r16  = lane & 15;
    const int st4  = stile * 4;

    floatx4 acc[4][4];
    #pragma unroll
    for (int mt = 0; mt < 4; ++mt)
        #pragma unroll
        for (int nt = 0; nt < 4; ++nt)
            acc[mt][nt] = (floatx4){0.f, 0.f, 0.f, 0.f};

    #pragma unroll
    for (int c = 0; c < 8; ++c) {
        short8 af[4], bf[4];
        #pragma unroll
        for (int mt = 0; mt < 4; ++mt)
            af[mt] = *(const short8*)(A + (size_t)((st4 + mt) * 8 + c) * 512 + lane * 8);
        #pragma unroll
        for (int nt = 0; nt < 4; ++nt)
            bf[nt] = *(const short8*)(Bm + (size_t)((w * 4 + nt) * 8 + c) * 512 + lane * 8);
        #pragma unroll
        for (int mt = 0; mt < 4; ++mt)
            #pragma unroll
            for (int nt = 0; nt < 4; ++nt)
                acc[mt][nt] = __builtin_amdgcn_mfma_f32_16x16x32_bf16(af[mt], bf[nt], acc[mt][nt], 0, 0, 0);
    }

    if (contr) {
        float pp[4][4];
        #pragma unroll
        for (int mt = 0; mt < 4; ++mt)
            #pragma unroll
            for (int reg = 0; reg < 4; ++reg) pp[mt][reg] = 0.f;

        #pragma unroll
        for (int mt = 0; mt < 4; ++mt)
            #pragma unroll
            for (int nt = 0; nt < 4; ++nt) {
                ushort4v t2q = *(const ushort4v*)(T2f + (size_t)stile * 16384
                                 + (size_t)((mt * 16 + (w * 4 + nt)) * 64 + lane) * 4);
                #pragma unroll
                for (int reg = 0; reg < 4; ++reg)
                    pp[mt][reg] += acc[mt][nt][reg] * bf2f(t2q[reg]);
            }

        #pragma unroll
        for (int mt = 0; mt < 4; ++mt)
            #pragma unroll
            for (int reg = 0; reg < 4; ++reg) {
                float v = pp[mt][reg];
                v += __shfl_xor(v, 1, 64);
                v += __shfl_xor(v, 2, 64);
                v += __shfl_xor(v, 4, 64);
                v += __shfl_xor(v, 8, 64);
                pp[mt][reg] = v;
            }
        if (r16 == 0) {
            #pragma unroll
            for (int mt = 0; mt < 4; ++mt)
                #pragma unroll
                for (int reg = 0; reg < 4; ++reg)
                    red[w][mt * 16 + g * 4 + reg] = pp[mt][reg];
        }
        __syncthreads();
        if (tid < 64) {
            float v = red[0][tid] + red[1][tid] + red[2][tid] + red[3][tid];
            int sg = sbase + tid;
            if (job == 0) out_trace[sg] = v;
            else          out_cdiv[(size_t)sg * Dd + (job - 1)] = v;
        }
    } else {
        const int n0 = (job - 33) * 256;
        #pragma unroll
        for (int mt = 0; mt < 4; ++mt)
            #pragma unroll
            for (int nt = 0; nt < 4; ++nt) {
                const int n = (w * 4 + nt) * 16 + r16;
                const float bias = cb3[n0 + n];
                #pragma unroll
                for (int reg = 0; reg < 4; ++reg) {
                    const int r = mt * 16 + g * 4 + reg;
                    out_cov[(size_t)(sbase + r) * 1024 + n0 + n] = acc[mt][nt][reg] + bias;
                }
            }
    }
}

// ============================================================================
extern "C" void kernel_launch(void* const* d_in, const int* in_sizes, int n_in,
                              void* d_out, int out_size, void* d_ws, size_t ws_size,
                              hipStream_t stream) {
    const float* x   = (const float*)d_in[0];
    const float* sW1 = (const float*)d_in[1];
    const float* sb1 = (const float*)d_in[2];
    const float* sW2 = (const float*)d_in[3];
    const float* sb2 = (const float*)d_in[4];
    const float* sW3 = (const float*)d_in[5];
    const float* sb3 = (const float*)d_in[6];
    const float* cW1 = (const float*)d_in[7];
    const float* cb1 = (const float*)d_in[8];
    const float* cW2 = (const float*)d_in[9];
    const float* cb2 = (const float*)d_in[10];
    const float* cW3 = (const float*)d_in[11];
    const float* cb3 = (const float*)d_in[12];

    const int B = in_sizes[0] / Dd;   // 2048

    float* out       = (float*)d_out;
    float* out_score = out;                                  // [B,32]
    float* out_trace = out + (size_t)B * Dd;                 // [B]
    float* out_cov   = out_trace + B;                        // [B,32,32]
    float* out_cdiv  = out_cov + (size_t)B * Dd * Dd;        // [B,32]

    unsigned short* ws16 = (unsigned short*)d_ws;
    const size_t SZ = (size_t)B * 256;
    unsigned short* T1s  = ws16;                             // A-frag
    unsigned short* T2s  = ws16 + SZ;                        // C-frag
    unsigned short* T1c  = ws16 + 2 * SZ;
    unsigned short* T2c  = ws16 + 3 * SZ;
    unsigned short* H2c  = ws16 + 4 * SZ;
    unsigned short* Mt   = ws16 + 5 * SZ;                    // [33] B-frag
    unsigned short* cW3t = Mt + (size_t)33 * 65536;          // B-frag
    unsigned short* sW2t = cW3t + (size_t)1024 * 256;        // A-frag
    unsigned short* cW2t = sW2t + (size_t)256 * 256;
    unsigned short* sW3t = cW2t + (size_t)256 * 256;         // A-frag [32 rows]
    unsigned short* W1ts = sW3t + (size_t)32 * 256;          // B-frag K=32
    unsigned short* W1tc = W1ts + (size_t)256 * 32;

    k1_prep<<<dim3(51), dim3(256), 0, stream>>>(
        sW1, sW2, sW3, cW1, cW2, cW3,
        cW3t, sW2t, cW2t, sW3t, W1ts, W1tc);

    ka_mfma<<<dim3(256 + 132), dim3(512), 0, stream>>>(
        x, sW1, sW2, sW3, cW1, cW2, cW3,
        W1ts, W1tc, sW2t, cW2t, sW3t,
        sb1, sb2, sb3, cb1, cb2,
        out_score, T1s, T2s, T1c, T2c, H2c, Mt);

    kb_mfma<<<dim3(B / 64, 37), dim3(256), 0, stream>>>(
        T1s, T2s, T1c, T2c, H2c, Mt, cW3t, cb3,
        out_trace, out_cdiv, out_cov);
}